// Round 1
// baseline (258.575 us; speedup 1.0000x reference)
//
#include <hip/hip_runtime.h>
#include <stdint.h>

// ---------------- problem constants ----------------
#define N_ELEMS   25165824   // 512*6*8192
#define K_TOTAL   98304u     // 32 * 512 * 6
#define EMA_RATE  0.003f

// ---------------- radix-select config ----------------
#define NBINS1     16384     // top 14 bits of key
#define BIN1_SHIFT 18
#define NBINS2     4096      // bits [17:6]
#define NBINS3     64        // bits [5:0]
#define LCAP       2048      // per-block LDS candidate staging
#define EQCAP      1024      // tie buffer

// monotone float->uint key: order(key) == order(float)
__device__ __forceinline__ unsigned f2key(float x) {
    unsigned u = __float_as_uint(x);
    return (u & 0x80000000u) ? ~u : (u | 0x80000000u);
}
__device__ __forceinline__ float key2f(unsigned key) {
    unsigned u = (key & 0x80000000u) ? (key & 0x7FFFFFFFu) : ~key;
    return __uint_as_float(u);
}

// ---------------- pass 1: 14-bit histogram ----------------
__global__ __launch_bounds__(512) void hist1_kernel(
        const float4* __restrict__ in, unsigned* __restrict__ ghist, int nvec) {
    __shared__ unsigned h[NBINS1];
    for (int i = threadIdx.x; i < NBINS1; i += blockDim.x) h[i] = 0;
    __syncthreads();
    int stride = gridDim.x * blockDim.x;
    for (int i = blockIdx.x * blockDim.x + threadIdx.x; i < nvec; i += stride) {
        float4 v = in[i];
        atomicAdd(&h[f2key(v.x) >> BIN1_SHIFT], 1u);
        atomicAdd(&h[f2key(v.y) >> BIN1_SHIFT], 1u);
        atomicAdd(&h[f2key(v.z) >> BIN1_SHIFT], 1u);
        atomicAdd(&h[f2key(v.w) >> BIN1_SHIFT], 1u);
    }
    __syncthreads();
    for (int i = threadIdx.x; i < NBINS1; i += blockDim.x) {
        unsigned c = h[i];
        if (c) atomicAdd(&ghist[i], c);
    }
}

// ---------------- find bin containing the k-th value ----------------
// res[0] = bin b ; res[1] = count of elements in bins strictly above b
__global__ __launch_bounds__(512) void find_bin_kernel(
        const unsigned* __restrict__ ghist, unsigned* __restrict__ res) {
    __shared__ unsigned psum[512];
    const int T = 512;
    const int GB = NBINS1 / T;              // 32 bins per thread, descending
    int t = threadIdx.x;
    int hi = NBINS1 - 1 - t * GB;
    unsigned s = 0;
    for (int j = 0; j < GB; ++j) s += ghist[hi - j];
    psum[t] = s;
    __syncthreads();
    for (int off = 1; off < T; off <<= 1) {   // inclusive Hillis-Steele
        unsigned o = (t >= off) ? psum[t - off] : 0u;
        __syncthreads();
        psum[t] += o;
        __syncthreads();
    }
    unsigned cum = psum[t] - s;               // elements above my group
    for (int j = 0; j < GB; ++j) {
        unsigned c = ghist[hi - j];
        if (cum < K_TOTAL && cum + c >= K_TOTAL) {
            res[0] = (unsigned)(hi - j);
            res[1] = cum;
        }
        cum += c;
    }
}

// ---------------- pass 2: write definite output + compact bin-b candidates --
__device__ __forceinline__ float proc_elem(
        float x, unsigned idx, unsigned b,
        float* lval, unsigned* lidx, unsigned* lcnt,
        float* cval, unsigned* cidx, unsigned* gcnt, unsigned cap) {
    unsigned bin = f2key(x) >> BIN1_SHIFT;
    if (bin < b) return 0.0f;
    if (bin > b) return fmaxf(x, 0.0f);
    unsigned p = atomicAdd(lcnt, 1u);
    if (p < LCAP) { lval[p] = x; lidx[p] = idx; }
    else {  // LDS overflow fallback (never expected for this data)
        unsigned g = atomicAdd(gcnt, 1u);
        if (g < cap) { cval[g] = x; cidx[g] = idx; }
    }
    return 0.0f;
}

__global__ __launch_bounds__(256) void pass2_kernel(
        const float4* __restrict__ in, float4* __restrict__ out,
        const unsigned* __restrict__ res,
        float* __restrict__ cval, unsigned* __restrict__ cidx,
        unsigned* __restrict__ gcnt, unsigned cap, int nvec) {
    __shared__ float    lval[LCAP];
    __shared__ unsigned lidx[LCAP];
    __shared__ unsigned lcnt;
    __shared__ unsigned base;
    if (threadIdx.x == 0) lcnt = 0;
    __syncthreads();
    unsigned b = res[0];
    int stride = gridDim.x * blockDim.x;
    for (int i = blockIdx.x * blockDim.x + threadIdx.x; i < nvec; i += stride) {
        float4 v = in[i];
        unsigned idx = 4u * (unsigned)i;
        float4 o;
        o.x = proc_elem(v.x, idx + 0u, b, lval, lidx, &lcnt, cval, cidx, gcnt, cap);
        o.y = proc_elem(v.y, idx + 1u, b, lval, lidx, &lcnt, cval, cidx, gcnt, cap);
        o.z = proc_elem(v.z, idx + 2u, b, lval, lidx, &lcnt, cval, cidx, gcnt, cap);
        o.w = proc_elem(v.w, idx + 3u, b, lval, lidx, &lcnt, cval, cidx, gcnt, cap);
        out[i] = o;
    }
    __syncthreads();
    unsigned n = min(lcnt, (unsigned)LCAP);
    if (threadIdx.x == 0) base = atomicAdd(gcnt, n);
    __syncthreads();
    for (unsigned j = threadIdx.x; j < n; j += blockDim.x) {
        unsigned p = base + j;
        if (p < cap) { cval[p] = lval[j]; cidx[p] = lidx[j]; }
    }
}

// ---------------- pass 3: refine 18 bits, scatter winners, ties, EMA -------
__global__ __launch_bounds__(1024) void pass3_kernel(
        const float* __restrict__ cval, const unsigned* __restrict__ cidx,
        const unsigned* __restrict__ gcnt, const unsigned* __restrict__ res,
        unsigned cap, float* __restrict__ out,
        const float* __restrict__ thr_in, float* __restrict__ thr_out) {
    __shared__ unsigned h2[NBINS2];
    __shared__ unsigned psum[1024];
    __shared__ unsigned h3[NBINS3];
    __shared__ unsigned eqidx[EQCAP];
    __shared__ unsigned eqcnt;
    __shared__ unsigned sh_b2, sh_need2, sh_b3, sh_need3;

    int t = threadIdx.x;
    unsigned nc   = min(*gcnt, cap);
    unsigned b    = res[0];
    unsigned need = K_TOTAL - res[1];         // winners to pick inside bin b

    for (int i = t; i < NBINS2; i += 1024) h2[i] = 0;
    if (t == 0) eqcnt = 0;
    __syncthreads();

    // histogram of bits [17:6]
    for (unsigned i = t; i < nc; i += 1024) {
        unsigned key = f2key(cval[i]);
        atomicAdd(&h2[(key >> 6) & (NBINS2 - 1)], 1u);
    }
    __syncthreads();

    // descending scan over 4096 bins (4 per thread)
    const int GB = NBINS2 / 1024;             // 4
    int hi = NBINS2 - 1 - t * GB;
    unsigned s = 0;
    for (int j = 0; j < GB; ++j) s += h2[hi - j];
    psum[t] = s;
    __syncthreads();
    for (int off = 1; off < 1024; off <<= 1) {
        unsigned o = (t >= off) ? psum[t - off] : 0u;
        __syncthreads();
        psum[t] += o;
        __syncthreads();
    }
    unsigned cum = psum[t] - s;
    for (int j = 0; j < GB; ++j) {
        unsigned c = h2[hi - j];
        if (cum < need && cum + c >= need) {
            sh_b2 = (unsigned)(hi - j);
            sh_need2 = need - cum;
        }
        cum += c;
    }
    __syncthreads();
    unsigned b2 = sh_b2, need2 = sh_need2;

    // histogram of bits [5:0] among subbin == b2
    for (int i = t; i < NBINS3; i += 1024) h3[i] = 0;
    __syncthreads();
    for (unsigned i = t; i < nc; i += 1024) {
        unsigned key = f2key(cval[i]);
        if (((key >> 6) & (NBINS2 - 1)) == b2) atomicAdd(&h3[key & 63u], 1u);
    }
    __syncthreads();
    if (t < NBINS3) {
        int bin = NBINS3 - 1 - t;
        unsigned cum3 = 0;
        for (int j = bin + 1; j < NBINS3; ++j) cum3 += h3[j];
        unsigned c = h3[bin];
        if (cum3 < need2 && cum3 + c >= need2) {
            sh_b3 = (unsigned)bin;
            sh_need3 = need2 - cum3;
        }
    }
    __syncthreads();
    unsigned keyv  = (b << BIN1_SHIFT) | (b2 << 6) | sh_b3;  // exact k-th key
    unsigned need3 = sh_need3;

    // scatter winners above keyv; collect exact ties
    for (unsigned i = t; i < nc; i += 1024) {
        float x = cval[i];
        unsigned key = f2key(x);
        if (key > keyv) {
            out[cidx[i]] = fmaxf(x, 0.0f);
        } else if (key == keyv) {
            unsigned p = atomicAdd(&eqcnt, 1u);
            if (p < EQCAP) eqidx[p] = cidx[i];
        }
    }
    __syncthreads();

    // tie-break: lax.top_k picks lowest flat indices first
    unsigned ne = min(eqcnt, (unsigned)EQCAP);
    float vv = key2f(keyv);
    for (unsigned e = t; e < ne; e += 1024) {
        unsigned my = eqidx[e];
        unsigned rank = 0;
        for (unsigned f = 0; f < ne; ++f) rank += (eqidx[f] < my) ? 1u : 0u;
        if (rank < need3) out[my] = fmaxf(vv, 0.0f);
    }

    if (t == 0) {
        float mink = fmaxf(vv, 0.0f);         // relu(k-th largest)
        thr_out[0] = (1.0f - EMA_RATE) * thr_in[0] + EMA_RATE * mink;
    }
}

// ---------------- launch ----------------
extern "C" void kernel_launch(void* const* d_in, const int* in_sizes, int n_in,
                              void* d_out, int out_size, void* d_ws, size_t ws_size,
                              hipStream_t stream) {
    const float* feat   = (const float*)d_in[0];
    const float* thr_in = (const float*)d_in[1];
    float* out = (float*)d_out;
    int N    = in_sizes[0];      // 25165824
    int nvec = N / 4;

    // workspace layout
    uint8_t* w = (uint8_t*)d_ws;
    unsigned* ghist = (unsigned*)w;                       // 64 KB
    unsigned* res   = (unsigned*)(w + (64 << 10));        // 64 B  (res[0]=bin, res[1]=count_above)
    unsigned* gcnt  = (unsigned*)(w + (64 << 10) + 64);   // candidate counter
    size_t cand_off = (size_t)(128 << 10);
    size_t cap_sz   = (ws_size > cand_off) ? (ws_size - cand_off) / 8 : 0;
    unsigned cap    = (unsigned)(cap_sz < (size_t)(1 << 20) ? cap_sz : (size_t)(1 << 20));
    float*    cval  = (float*)(w + cand_off);
    unsigned* cidx  = (unsigned*)(w + cand_off + (size_t)cap * 4);

    // zero histogram + counters (ws is re-poisoned before every launch)
    hipMemsetAsync(d_ws, 0, (64 << 10) + 128, stream);

    hist1_kernel  <<<1024, 512, 0, stream>>>((const float4*)feat, ghist, nvec);
    find_bin_kernel<<<1,   512, 0, stream>>>(ghist, res);
    pass2_kernel  <<<2048, 256, 0, stream>>>((const float4*)feat, (float4*)out, res,
                                             cval, cidx, gcnt, cap, nvec);
    pass3_kernel  <<<1,   1024, 0, stream>>>(cval, cidx, gcnt, res, cap,
                                             out, thr_in, out + N);
}